// Round 3
// baseline (675.229 us; speedup 1.0000x reference)
//
#include <hip/hip_runtime.h>

// AttnBlock: B=4, C=512, N=H*W=4096.
// Pipeline: prep(weights->bf16) ; transpose(x->xT bf16) ; QKV GEMM (bf16 MFMA)
//   -> Qt[n][c]*scale, Kt[n][c], V[c][n] ; flash attention (KV split 2) ; combine ;
//   proj GEMM + bias + residual (fp32 out).
// Workspace use ~120 MB.

using u16 = unsigned short;
using u32 = unsigned int;
using h8   = __attribute__((ext_vector_type(8))) short;   // 8 x bf16 (one MFMA A/B frag)
using fx4  = __attribute__((ext_vector_type(4))) float;   // MFMA C/D frag
using q16  = __attribute__((ext_vector_type(4))) u32;     // 16-byte chunk
using u16x4= __attribute__((ext_vector_type(4))) u16;

#define BB 4
#define CC 512
#define NN 4096
#define NBE ((size_t)BB * NN * CC)   // 8388608 elements per (B,N,C) tensor

__device__ __forceinline__ u16 f2b(float f) {          // fp32 -> bf16 RNE
  u32 u = __float_as_uint(f);
  u = (u + 0x7fffu + ((u >> 16) & 1u)) >> 16;
  return (u16)u;
}
__device__ __forceinline__ float b2f(u16 h) { return __uint_as_float(((u32)h) << 16); }

// ---------------- prep: weights -> bf16 ----------------
__global__ void k_prep(const float* __restrict__ qw, const float* __restrict__ pw,
                       u16* __restrict__ wqb, u16* __restrict__ wpb) {
  int i = blockIdx.x * 256 + threadIdx.x;
  if (i < 1536 * 512) wqb[i] = f2b(qw[i]);
  if (i < 512 * 512)  wpb[i] = f2b(pw[i]);
}

// ---------------- transpose: x (B,C,N) fp32 -> xt (B,N,C) bf16 ----------------
__global__ __launch_bounds__(256) void k_txp(const float* __restrict__ x, u16* __restrict__ xt) {
  // grid = B * (C/64) * (N/64) = 4*8*64 = 2048
  int bid = blockIdx.x;
  int nb = bid & 63; int cb = (bid >> 6) & 7; int b = bid >> 9;
  __shared__ float t[64][65];
  const float* xb = x + (size_t)b * CC * NN;
  for (int k = 0; k < 16; ++k) {
    int idx = k * 256 + threadIdx.x;
    int r = idx >> 6, col = idx & 63;
    t[r][col] = xb[(size_t)(cb * 64 + r) * NN + nb * 64 + col];
  }
  __syncthreads();
  u16* xtb = xt + (size_t)b * NN * CC;
  for (int k = 0; k < 16; ++k) {
    int idx = k * 256 + threadIdx.x;
    int nr = idx >> 6, cc = idx & 63;
    xtb[(size_t)(nb * 64 + nr) * CC + cb * 64 + cc] = f2b(t[cc][nr]);
  }
}

// ---------------- shared 128x128 GEMM mainloop (K=512, BK=64) ----------------
// A rows: M-tile (k-contiguous bf16), B rows: N-tile (k-contiguous bf16).
// LDS rows of 8 16B slots, slot XOR (row&7) swizzle (kills 16-way bank conflict).
__device__ __forceinline__ void gemm_mm(const char* __restrict__ Ab, const char* __restrict__ Bb,
                                        q16* aT, q16* bT, fx4 (&acc)[4][4], int tid) {
  const int lane = tid & 63, wv = tid >> 6;
  const int wm = wv >> 1, wn = wv & 1, g = lane >> 4, r = lane & 15;
  for (int kb = 0; kb < 8; ++kb) {
    __syncthreads();
#pragma unroll
    for (int it = 0; it < 4; ++it) {
      int idx = it * 256 + tid; int row = idx >> 3, slot = idx & 7;
      size_t go = (size_t)row * 1024 + (size_t)kb * 128 + (size_t)slot * 16;
      aT[row * 8 + (slot ^ (row & 7))] = *(const q16*)(Ab + go);
      bT[row * 8 + (slot ^ (row & 7))] = *(const q16*)(Bb + go);
    }
    __syncthreads();
#pragma unroll
    for (int ks = 0; ks < 2; ++ks) {
      h8 af[4], bf[4];
#pragma unroll
      for (int mt = 0; mt < 4; ++mt) { int row = wm * 64 + mt * 16 + r; af[mt] = *(const h8*)&aT[row * 8 + ((ks * 4 + g) ^ (row & 7))]; }
#pragma unroll
      for (int nt = 0; nt < 4; ++nt) { int row = wn * 64 + nt * 16 + r; bf[nt] = *(const h8*)&bT[row * 8 + ((ks * 4 + g) ^ (row & 7))]; }
#pragma unroll
      for (int mt = 0; mt < 4; ++mt)
#pragma unroll
        for (int nt = 0; nt < 4; ++nt)
          acc[mt][nt] = __builtin_amdgcn_mfma_f32_16x16x32_bf16(af[mt], bf[nt], acc[mt][nt], 0, 0, 0);
    }
  }
}

// ---------------- QKV GEMM: D[o][n] = wq[o][:] . xt[n][:] + b[o] ----------------
__global__ __launch_bounds__(256) void k_qkv(const u16* __restrict__ wqb, const u16* __restrict__ xt,
                                             const float* __restrict__ qkvb,
                                             u16* __restrict__ qt, u16* __restrict__ kt, u16* __restrict__ vv) {
  __shared__ q16 aT[1024], bT[1024];
  int bid = blockIdx.x;                  // grid = 4 * 12 * 32 = 1536
  int nb = bid & 31; int mb = (bid >> 5) % 12; int b = bid / 384;
  int ob = mb * 128, n0 = nb * 128;
  int tid = threadIdx.x, lane = tid & 63, wv = tid >> 6;
  int wm = wv >> 1, wn = wv & 1, g = lane >> 4, r = lane & 15;
  fx4 acc[4][4] = {};
  gemm_mm((const char*)(wqb + (size_t)ob * CC),
          (const char*)(xt + ((size_t)b * NN + n0) * CC), aT, bT, acc, tid);
  int region = mb >> 2;                  // 0=Q 1=K 2=V
#pragma unroll
  for (int mt = 0; mt < 4; ++mt) {
    int o_b = ob + wm * 64 + mt * 16 + g * 4;
#pragma unroll
    for (int nt = 0; nt < 4; ++nt) {
      int n = n0 + wn * 64 + nt * 16 + r;
      if (region == 2) {
#pragma unroll
        for (int rr = 0; rr < 4; ++rr) {
          int o = o_b + rr;
          float v = acc[mt][nt][rr] + qkvb[o];
          vv[((size_t)b * CC + (o - 1024)) * NN + n] = f2b(v);
        }
      } else {
        u16x4 pk;
#pragma unroll
        for (int rr = 0; rr < 4; ++rr) {
          int o = o_b + rr;
          float v = acc[mt][nt][rr] + qkvb[o];
          if (region == 0) v *= 0.044194173824159216f;   // 1/sqrt(512) folded into Q
          pk[rr] = f2b(v);
        }
        u16* dst = (region == 0 ? qt : kt) + ((size_t)b * NN + n) * CC + (o_b - region * 512);
        *(u16x4*)dst = pk;
      }
    }
  }
}

// ---------------- flash attention, KV split = 2 ----------------
// 256 thr, BQ=64 (16 rows/wave), BKV=32. Q in regs; K,V LDS-staged; P via LDS.
__global__ __launch_bounds__(256, 2) void k_attn(const u16* __restrict__ qt, const u16* __restrict__ kt,
                                                 const u16* __restrict__ vv,
                                                 u16* __restrict__ op, float* __restrict__ ml) {
  __shared__ q16 kT[2048];                       // [32 j][64 slots] swz8 : 32KB
  __shared__ q16 vT[2048];                       // [512 c][4 chunks of 8 j] : 32KB
  __shared__ __align__(16) u16 pT[4][16][40];    // per-wave P tile, padded
  int bid = blockIdx.x;                          // grid = 2 * 4 * 64 = 512
  int qb = (bid & 63) * 64; int b = (bid >> 6) & 3; int part = bid >> 8;
  int tid = threadIdx.x, lane = tid & 63, wv = tid >> 6;
  int g = lane >> 4, r = lane & 15;
  const u16* qtb = qt + ((size_t)b * NN + qb) * CC;
  const u16* ktb = kt + (size_t)b * NN * CC;
  const u16* vvb = vv + (size_t)b * CC * NN;

  h8 qf[16];                                     // 16 k-steps of Q rows (this wave: rows wv*16 + r)
  const u16* qrow = qtb + (size_t)(wv * 16 + r) * CC + g * 8;
#pragma unroll
  for (int ks = 0; ks < 16; ++ks) qf[ks] = *(const h8*)(qrow + ks * 32);

  fx4 oa[32] = {};
  float m_r[4] = {-1e30f, -1e30f, -1e30f, -1e30f};
  float l_r[4] = {0.f, 0.f, 0.f, 0.f};
  int j0 = part * 2048;

  for (int jt = 0; jt < 64; ++jt) {
    int jb = j0 + jt * 32;
    __syncthreads();
#pragma unroll
    for (int it = 0; it < 8; ++it) {             // K tile: rows j (k-contig), swz8
      int idx = it * 256 + tid; int row = idx >> 6, slot = idx & 63;
      kT[row * 64 + (slot ^ (row & 7))] = *(const q16*)((const char*)(ktb + (size_t)(jb + row) * CC) + slot * 16);
    }
#pragma unroll
    for (int it = 0; it < 8; ++it) {             // V tile: [c][32 j] linear
      int idx = it * 256 + tid; int c = idx >> 2, gg = idx & 3;
      vT[idx] = *(const q16*)(vvb + (size_t)c * NN + jb + gg * 8);
    }
    __syncthreads();

    fx4 s[2] = {};                               // S strip: 16 i x 32 j
#pragma unroll
    for (int ks = 0; ks < 16; ++ks) {
#pragma unroll
      for (int nt = 0; nt < 2; ++nt) {
        int row = nt * 16 + r;
        h8 kf = *(const h8*)&kT[row * 64 + ((ks * 4 + g) ^ (row & 7))];
        s[nt] = __builtin_amdgcn_mfma_f32_16x16x32_bf16(qf[ks], kf, s[nt], 0, 0, 0);
      }
    }
    // online softmax (rows i = wv*16 + g*4 + rr, reduce over j = lanes&15 and nt)
    float tm[4], p0[4], p1[4], rs[4], alpha[4];
#pragma unroll
    for (int rr = 0; rr < 4; ++rr) tm[rr] = fmaxf(s[0][rr], s[1][rr]);
#pragma unroll
    for (int mask = 1; mask < 16; mask <<= 1)
#pragma unroll
      for (int rr = 0; rr < 4; ++rr) tm[rr] = fmaxf(tm[rr], __shfl_xor(tm[rr], mask));
#pragma unroll
    for (int rr = 0; rr < 4; ++rr) {
      float mn = fmaxf(m_r[rr], tm[rr]);
      alpha[rr] = __expf(m_r[rr] - mn);
      m_r[rr] = mn;
      p0[rr] = __expf(s[0][rr] - mn);
      p1[rr] = __expf(s[1][rr] - mn);
      rs[rr] = p0[rr] + p1[rr];
    }
#pragma unroll
    for (int mask = 1; mask < 16; mask <<= 1)
#pragma unroll
      for (int rr = 0; rr < 4; ++rr) rs[rr] += __shfl_xor(rs[rr], mask);
#pragma unroll
    for (int rr = 0; rr < 4; ++rr) l_r[rr] = l_r[rr] * alpha[rr] + rs[rr];
#pragma unroll
    for (int ct = 0; ct < 32; ++ct) { fx4 t = oa[ct];
#pragma unroll
      for (int rr = 0; rr < 4; ++rr) t[rr] *= alpha[rr]; oa[ct] = t; }
    // P -> LDS (wave-private), then A-frag read
#pragma unroll
    for (int rr = 0; rr < 4; ++rr) {
      pT[wv][g * 4 + rr][r]      = f2b(p0[rr]);
      pT[wv][g * 4 + rr][16 + r] = f2b(p1[rr]);
    }
    h8 pf = *(const h8*)&pT[wv][r][g * 8];
#pragma unroll
    for (int ct = 0; ct < 32; ++ct) {
      h8 vf = *(const h8*)&vT[(ct * 16 + r) * 4 + g];
      oa[ct] = __builtin_amdgcn_mfma_f32_16x16x32_bf16(pf, vf, oa[ct], 0, 0, 0);
    }
  }
  // epilogue: unnormalized O (bf16) + m,l
  size_t obase = (((size_t)part * BB + b) * NN + qb) * CC;
#pragma unroll
  for (int ct = 0; ct < 32; ++ct)
#pragma unroll
    for (int rr = 0; rr < 4; ++rr) {
      int i = wv * 16 + g * 4 + rr; int c = ct * 16 + r;
      op[obase + (size_t)i * CC + c] = f2b(oa[ct][rr]);
    }
  if (r == 0) {
#pragma unroll
    for (int rr = 0; rr < 4; ++rr) {
      int i = qb + wv * 16 + g * 4 + rr;
      ml[(((size_t)part * BB + b) * 2 + 0) * NN + i] = m_r[rr];
      ml[(((size_t)part * BB + b) * 2 + 1) * NN + i] = l_r[rr];
    }
  }
}

// ---------------- combine the 2 KV-split partials -> Ht (B,N,C) bf16 ----------------
__global__ __launch_bounds__(256) void k_comb(const u16* __restrict__ op, const float* __restrict__ ml,
                                              u16* __restrict__ ht) {
  int row = blockIdx.x * 4 + (threadIdx.x >> 6);   // grid 4096 -> 16384 rows
  int lane = threadIdx.x & 63;
  int b = row >> 12; int i = row & 4095;
  float m1 = ml[(((size_t)0 * BB + b) * 2 + 0) * NN + i];
  float l1 = ml[(((size_t)0 * BB + b) * 2 + 1) * NN + i];
  float m2 = ml[(((size_t)1 * BB + b) * 2 + 0) * NN + i];
  float l2 = ml[(((size_t)1 * BB + b) * 2 + 1) * NN + i];
  float m = fmaxf(m1, m2);
  float w1 = __expf(m1 - m), w2 = __expf(m2 - m);
  float inv = 1.0f / (w1 * l1 + w2 * l2);
  const u16* o1 = op + ((size_t)b * NN + i) * CC + lane * 8;
  const u16* o2 = o1 + NBE;
  h8 a = *(const h8*)o1; h8 c = *(const h8*)o2;
  u16 res[8];
#pragma unroll
  for (int e = 0; e < 8; ++e)
    res[e] = f2b((b2f((u16)a[e]) * w1 + b2f((u16)c[e]) * w2) * inv);
  h8 pk = *(const h8*)res;
  *(h8*)(ht + ((size_t)b * NN + i) * CC + lane * 8) = pk;
}

// ---------------- proj GEMM + bias + residual: out[b][o][n] (fp32) ----------------
__global__ __launch_bounds__(256) void k_proj(const u16* __restrict__ ht, const u16* __restrict__ wpb,
                                              const float* __restrict__ pb, const float* __restrict__ x,
                                              float* __restrict__ out) {
  __shared__ q16 aT[1024], bT[1024];
  int bid = blockIdx.x;                   // grid = 4 * 32 * 4 = 512
  int ot = bid & 3; int ntile = (bid >> 2) & 31; int b = bid >> 7;
  int n0 = ntile * 128, o0 = ot * 128;
  int tid = threadIdx.x, lane = tid & 63, wv = tid >> 6;
  int wm = wv >> 1, wn = wv & 1, g = lane >> 4, r = lane & 15;
  fx4 acc[4][4] = {};
  gemm_mm((const char*)(ht + ((size_t)b * NN + n0) * CC),
          (const char*)(wpb + (size_t)o0 * CC), aT, bT, acc, tid);
  const float* xb = x + (size_t)b * CC * NN;
  float* ob_ = out + (size_t)b * CC * NN;
#pragma unroll
  for (int nt = 0; nt < 4; ++nt) {
    int o = o0 + wn * 64 + nt * 16 + r;
    float bias = pb[o];
#pragma unroll
    for (int mt = 0; mt < 4; ++mt) {
      int n = n0 + wm * 64 + mt * 16 + g * 4;
      fx4 xv = *(const fx4*)(xb + (size_t)o * NN + n);
      fx4 res;
#pragma unroll
      for (int rr = 0; rr < 4; ++rr) res[rr] = acc[mt][nt][rr] + bias + xv[rr];
      *(fx4*)(ob_ + (size_t)o * NN + n) = res;
    }
  }
}

extern "C" void kernel_launch(void* const* d_in, const int* in_sizes, int n_in,
                              void* d_out, int out_size, void* d_ws, size_t ws_size,
                              hipStream_t stream) {
  const float* x  = (const float*)d_in[0];
  const float* qw = (const float*)d_in[1];
  const float* qb = (const float*)d_in[2];
  const float* pw = (const float*)d_in[3];
  const float* pb = (const float*)d_in[4];
  float* out = (float*)d_out;

  u16* ws  = (u16*)d_ws;                   // ~120 MB total
  u16* qt  = ws;                           // (B,N,C) bf16, scale folded
  u16* kt  = qt + NBE;                     // (B,N,C)
  u16* vv  = kt + NBE;                     // (B,C,N)
  u16* xt  = vv + NBE;                     // (B,N,C)
  u16* ht  = xt + NBE;                     // (B,N,C)
  u16* wqb = ht + NBE;                     // 1536x512
  u16* wpb = wqb + 1536 * 512;             // 512x512
  u16* op  = wpb + 512 * 512;              // 2 x (B,N,C) partial O
  float* ml = (float*)(op + 2 * NBE);      // [2][B][2][N]

  hipLaunchKernelGGL(k_prep, dim3(3072), dim3(256), 0, stream, qw, pw, wqb, wpb);
  hipLaunchKernelGGL(k_txp,  dim3(2048), dim3(256), 0, stream, x, xt);
  hipLaunchKernelGGL(k_qkv,  dim3(1536), dim3(256), 0, stream, wqb, xt, qb, qt, kt, vv);
  hipLaunchKernelGGL(k_attn, dim3(512),  dim3(256), 0, stream, qt, kt, vv, op, ml);
  hipLaunchKernelGGL(k_comb, dim3(4096), dim3(256), 0, stream, op, ml, ht);
  hipLaunchKernelGGL(k_proj, dim3(512),  dim3(256), 0, stream, ht, wpb, pb, x, out);
}